// Round 2
// baseline (103.625 us; speedup 1.0000x reference)
//
#include <hip/hip_runtime.h>

// IntSoftmax_Piecewise: integer softmax with piecewise deg-2 int-exp.
// out[r*1024+j] = softmax_int/128 ; out[rows*1024] = s_out = 1/128.
// The reference's straight-through float-softmax combine is numerically the
// identity on si (sf - sf == 0 elementwise; floor(si/s_out)*s_out == si), so
// the float softmax is never computed here.
//
// Bit-exactness notes:
//  - Horner on integer-valued f32 with |intermediate| < 2^24 is EXACT, so FMA
//    vs mul+add is moot there; __fmul_rn/__fadd_rn used anyway for safety.
//  - The only rounded ops are x/s, 2^32/sum, e*factor -> __fdiv_rn/__fmul_rn
//    (IEEE RN, matches the numpy/jax f32 reference per-op).
//  - Row max/sum are over integer-valued f32 -> order-independent, exact.

constexpr int ROW = 1024;
constexpr int WPB = 4;  // one row per wave, 4 waves per 256-thread block

__global__ __launch_bounds__(256) void intsoftmax_kernel(
    const float* __restrict__ x,
    const float* __restrict__ s_ptr,
    const float* __restrict__ lo_bounds,
    const float* __restrict__ coeffs,   // [16][3], highest power first
    float* __restrict__ out,
    int rows)
{
    __shared__ float4 sc[16];
    const int tid = threadIdx.x;
    if (tid < 16) {
        sc[tid] = make_float4(coeffs[tid * 3 + 0],
                              coeffs[tid * 3 + 1],
                              coeffs[tid * 3 + 2], 0.0f);
    }
    __syncthreads();

    if (blockIdx.x == 0 && tid == 0) {
        out[(size_t)rows * ROW] = 0.0078125f;  // second tuple output: s_out
    }

    const float s = s_ptr[0];

    // wave-uniform bounds -> scalar loads/SGPRs
    float lo[16];
#pragma unroll
    for (int i = 0; i < 16; ++i) lo[i] = lo_bounds[i];

    const int wave = tid >> 6;
    const int lane = tid & 63;
    const long long row = (long long)blockIdx.x * WPB + wave;
    if (row >= rows) return;

    // 1024 elements/row = 64 lanes x 4 float4 chunks (16 elems/lane)
    const float4* __restrict__ xr = (const float4*)(x + row * (long long)ROW);

    float xi[16];
#pragma unroll
    for (int c = 0; c < 4; ++c) {
        const float4 v = xr[c * 64 + lane];
        xi[c * 4 + 0] = floorf(__fdiv_rn(v.x, s));
        xi[c * 4 + 1] = floorf(__fdiv_rn(v.y, s));
        xi[c * 4 + 2] = floorf(__fdiv_rn(v.z, s));
        xi[c * 4 + 3] = floorf(__fdiv_rn(v.w, s));
    }

    // rowwise max (exact: integer-valued floats)
    float m = xi[0];
#pragma unroll
    for (int k = 1; k < 16; ++k) m = fmaxf(m, xi[k]);
#pragma unroll
    for (int off = 32; off >= 1; off >>= 1)
        m = fmaxf(m, __shfl_xor(m, off, 64));

    // per-element: segment select + Horner + clip + /2^15 floor
    float e[16];
    float psum = 0.0f;
#pragma unroll
    for (int k = 0; k < 16; ++k) {
        const float xv = xi[k] - m;  // exact (integer-valued, < 2^24)
        int seg = 0;
#pragma unroll
        for (int i = 1; i < 16; ++i) seg += (xv >= lo[i]) ? 1 : 0;
        const float4 c = sc[seg];
        float r = __fadd_rn(__fmul_rn(c.x, xv), c.y);
        r = __fadd_rn(__fmul_rn(r, xv), c.z);
        r = fmaxf(r, 0.0f);
        e[k] = floorf(r * (1.0f / 32768.0f));  // exact pow2 scale
        psum += e[k];                          // exact small-int sum
    }

    // rowwise sum
    float sum = psum;
#pragma unroll
    for (int off = 32; off >= 1; off >>= 1)
        sum += __shfl_xor(sum, off, 64);

    const float factor = floorf(__fdiv_rn(4294967296.0f, fmaxf(sum, 1.0f)));

    // softmax_int = floor(e * factor / 2^25); out = softmax_int * 2^-7
    float4* __restrict__ orow = (float4*)(out + row * (long long)ROW);
#pragma unroll
    for (int c = 0; c < 4; ++c) {
        float4 o;
        o.x = floorf(__fmul_rn(e[c*4+0], factor) * (1.0f/33554432.0f)) * 0.0078125f;
        o.y = floorf(__fmul_rn(e[c*4+1], factor) * (1.0f/33554432.0f)) * 0.0078125f;
        o.z = floorf(__fmul_rn(e[c*4+2], factor) * (1.0f/33554432.0f)) * 0.0078125f;
        o.w = floorf(__fmul_rn(e[c*4+3], factor) * (1.0f/33554432.0f)) * 0.0078125f;
        orow[c * 64 + lane] = o;
    }
}

extern "C" void kernel_launch(void* const* d_in, const int* in_sizes, int n_in,
                              void* d_out, int out_size, void* d_ws, size_t ws_size,
                              hipStream_t stream) {
    const float* x      = (const float*)d_in[0];
    const float* s      = (const float*)d_in[1];
    const float* lo     = (const float*)d_in[2];
    // d_in[3] = hi_bounds (unused: segments contiguous, lo alone decides)
    const float* coeffs = (const float*)d_in[4];
    float* out = (float*)d_out;

    const int n = in_sizes[0];
    const int rows = n / ROW;
    const int blocks = (rows + WPB - 1) / WPB;

    hipLaunchKernelGGL(intsoftmax_kernel, dim3(blocks), dim3(256), 0, stream,
                       x, s, lo, coeffs, out, rows);
}

// Round 4
// 59.555 us; speedup vs baseline: 1.7400x; 1.7400x over previous
//
#include <hip/hip_runtime.h>

// IntSoftmax_Piecewise: integer softmax with piecewise deg-2 int-exp.
// out[r*1024+j] = softmax_int/128 ; out[rows*1024] = s_out = 1/128.
// The reference's straight-through float-softmax combine is numerically the
// identity on si, so the float softmax is never computed.
//
// Structure:
//  - e(xv) = floor(max(Horner(xv),0)/2^15) is a pure function of the integer
//    xv = x_int - rowmax in [-~1200, 0]. Precompute a 2048-entry LDS table per
//    block (exact same f32 ops => bit-identical), then 1 ds_read per element
//    instead of 15-compare segment scan + Horner (~35 VALU ops).
//  - floor(x/s) via Markstein correctly-rounded FMA division (4 ops vs ~11):
//    r=RN(1/s); q0=RN(x*r); q=RN(fma(fma(-s,q0,x), r, q0)) == RN(x/s).
//  - xv below table range (needs logit spread > 20.47; actual ~11.3) falls
//    back to the exact direct path, taken wave-uniformly => correctness never
//    depends on the data range.

constexpr int ROW = 1024;
constexpr int WPB = 4;        // one row per wave, 4 waves per 256-thread block
constexpr int TSIZE = 2048;   // table covers xv in [-(TSIZE-1), 0]

typedef float f32x4 __attribute__((ext_vector_type(4)));

__global__ __launch_bounds__(256) void intsoftmax_kernel(
    const float* __restrict__ x,
    const float* __restrict__ s_ptr,
    const float* __restrict__ lo_bounds,
    const float* __restrict__ coeffs,   // [16][3], highest power first
    float* __restrict__ out,
    int rows)
{
    __shared__ float4 sc[16];
    __shared__ float slo[16];
    __shared__ float etab[TSIZE];

    const int tid = threadIdx.x;
    if (tid < 16) {
        sc[tid] = make_float4(coeffs[tid * 3 + 0],
                              coeffs[tid * 3 + 1],
                              coeffs[tid * 3 + 2], 0.0f);
        slo[tid] = lo_bounds[tid];
    }
    __syncthreads();

    // Build e-table: etab[i] = e(i - (TSIZE-1)), exact reference ops.
    for (int i = tid; i < TSIZE; i += 256) {
        const float xv = (float)(i - (TSIZE - 1));
        int seg = 0;
#pragma unroll
        for (int j = 1; j < 16; ++j) seg += (xv >= slo[j]) ? 1 : 0;
        const float4 c = sc[seg];
        float r = __fadd_rn(__fmul_rn(c.x, xv), c.y);
        r = __fadd_rn(__fmul_rn(r, xv), c.z);
        etab[i] = floorf(fmaxf(r, 0.0f) * (1.0f / 32768.0f));
    }
    __syncthreads();

    if (blockIdx.x == 0 && tid == 0) {
        out[(size_t)rows * ROW] = 0.0078125f;  // second tuple output: s_out
    }

    const float s = s_ptr[0];
    const float rcp = __fdiv_rn(1.0f, s);  // RN(1/s), once

    const int wave = tid >> 6;
    const int lane = tid & 63;
    const long long row = (long long)blockIdx.x * WPB + wave;
    if (row >= rows) return;

    const float4* __restrict__ xr = (const float4*)(x + row * (long long)ROW);

    // x_int = floor(RN(x/s)) via Markstein correctly-rounded division
    float xi[16];
#pragma unroll
    for (int c4 = 0; c4 < 4; ++c4) {
        const float4 v = xr[c4 * 64 + lane];
        {
            const float q0 = __fmul_rn(v.x, rcp);
            xi[c4*4+0] = floorf(__builtin_fmaf(__builtin_fmaf(-s, q0, v.x), rcp, q0));
        }
        {
            const float q0 = __fmul_rn(v.y, rcp);
            xi[c4*4+1] = floorf(__builtin_fmaf(__builtin_fmaf(-s, q0, v.y), rcp, q0));
        }
        {
            const float q0 = __fmul_rn(v.z, rcp);
            xi[c4*4+2] = floorf(__builtin_fmaf(__builtin_fmaf(-s, q0, v.z), rcp, q0));
        }
        {
            const float q0 = __fmul_rn(v.w, rcp);
            xi[c4*4+3] = floorf(__builtin_fmaf(__builtin_fmaf(-s, q0, v.w), rcp, q0));
        }
    }

    // rowwise max (exact: integer-valued floats)
    float m = xi[0];
#pragma unroll
    for (int k = 1; k < 16; ++k) m = fmaxf(m, xi[k]);
#pragma unroll
    for (int off = 32; off >= 1; off >>= 1)
        m = fmaxf(m, __shfl_xor(m, off, 64));

    // table indices; imin tracks whether any element is below table range
    int idx[16];
    int imin = 0;
#pragma unroll
    for (int k = 0; k < 16; ++k) {
        idx[k] = (int)(xi[k] - m) + (TSIZE - 1);  // exact int-valued subtract
        imin = min(imin, idx[k]);
    }

    float e[16];
    float psum = 0.0f;
    if (__builtin_expect(!__any(imin < 0), 1)) {
        // fast path: pure table lookups
#pragma unroll
        for (int k = 0; k < 16; ++k) {
            e[k] = etab[idx[k]];
            psum += e[k];
        }
    } else {
        // exact fallback (wave-uniform branch; ~never taken for sane data)
#pragma unroll
        for (int k = 0; k < 16; ++k) {
            const float xv = xi[k] - m;
            int seg = 0;
#pragma unroll
            for (int j = 1; j < 16; ++j) seg += (xv >= slo[j]) ? 1 : 0;
            const float4 c = sc[seg];
            float r = __fadd_rn(__fmul_rn(c.x, xv), c.y);
            r = __fadd_rn(__fmul_rn(r, xv), c.z);
            e[k] = floorf(fmaxf(r, 0.0f) * (1.0f / 32768.0f));
            psum += e[k];
        }
    }

    // rowwise sum (exact small-int f32, order-free)
    float sum = psum;
#pragma unroll
    for (int off = 32; off >= 1; off >>= 1)
        sum += __shfl_xor(sum, off, 64);

    const float factor = floorf(__fdiv_rn(4294967296.0f, fmaxf(sum, 1.0f)));

    // softmax_int = floor(RN(e*factor) / 2^25); out = softmax_int * 2^-7
    f32x4* const orow_v = (f32x4*)(out + row * (long long)ROW);
#pragma unroll
    for (int c4 = 0; c4 < 4; ++c4) {
        f32x4 o;
        o.x = floorf(__fmul_rn(e[c4*4+0], factor) * (1.0f/33554432.0f)) * 0.0078125f;
        o.y = floorf(__fmul_rn(e[c4*4+1], factor) * (1.0f/33554432.0f)) * 0.0078125f;
        o.z = floorf(__fmul_rn(e[c4*4+2], factor) * (1.0f/33554432.0f)) * 0.0078125f;
        o.w = floorf(__fmul_rn(e[c4*4+3], factor) * (1.0f/33554432.0f)) * 0.0078125f;
        __builtin_nontemporal_store(o, orow_v + c4 * 64 + lane);
    }
}

extern "C" void kernel_launch(void* const* d_in, const int* in_sizes, int n_in,
                              void* d_out, int out_size, void* d_ws, size_t ws_size,
                              hipStream_t stream) {
    const float* x      = (const float*)d_in[0];
    const float* s      = (const float*)d_in[1];
    const float* lo     = (const float*)d_in[2];
    // d_in[3] = hi_bounds (unused: segments contiguous, lo alone decides)
    const float* coeffs = (const float*)d_in[4];
    float* out = (float*)d_out;

    const int n = in_sizes[0];
    const int rows = n / ROW;
    const int blocks = (rows + WPB - 1) / WPB;

    hipLaunchKernelGGL(intsoftmax_kernel, dim3(blocks), dim3(256), 0, stream,
                       x, s, lo, coeffs, out, rows);
}